// Round 2
// baseline (176.153 us; speedup 1.0000x reference)
//
#include <hip/hip_runtime.h>

// FFF tree traversal, round 2.
// BATCH=32768, N_IN=N_OUT=1024, 11 levels, 2047 nodes.
// One wave = 2 independent rows (interleaved chains for ILP).
// Cache policy: x / y / deep-level (l>=9) weights are nontemporal so the
// shallow weight set (levels 0-8, ~3 MB incl. bf16 w2) stays L2-resident.
// w2 is converted to bf16 in a prep kernel (output-only, no sign sensitivity).

typedef float          f32x4 __attribute__((ext_vector_type(4)));
typedef unsigned short u16x4 __attribute__((ext_vector_type(4)));

#define FFF_BATCH  32768
#define FFF_NIN    1024
#define FFF_NOUT   1024
#define FFF_LEVELS 11
#define FFF_NODES  2047

__device__ __forceinline__ f32x4 ld_nt4f(const f32x4* p) { return __builtin_nontemporal_load(p); }
__device__ __forceinline__ u16x4 ld_nt4u(const u16x4* p) { return __builtin_nontemporal_load(p); }

// ---- prep: w2 fp32 -> bf16 (RNE) into workspace ----
__global__ void fff_w2_to_bf16(const float* __restrict__ w2, unsigned short* __restrict__ o)
{
    const int i = blockIdx.x * blockDim.x + threadIdx.x;   // one float4 per thread
    const f32x4 v = reinterpret_cast<const f32x4*>(w2)[i];
    u16x4 u;
#pragma unroll
    for (int k = 0; k < 4; ++k) {
        unsigned b = __float_as_uint(v[k]);
        b = (b + 0x7FFFu + ((b >> 16) & 1u)) >> 16;        // round-to-nearest-even
        u[k] = (unsigned short)b;
    }
    reinterpret_cast<u16x4*>(o)[i] = u;
}

template<bool W2BF16>
__global__ __launch_bounds__(256, 4) void fff_main(
    const float* __restrict__ x,
    const float* __restrict__ w1s,
    const void*  __restrict__ w2p,
    float* __restrict__ y)
{
    const int wave = threadIdx.x >> 6;
    const int lane = threadIdx.x & 63;
    const int row0 = (blockIdx.x * 4 + wave) * 2;          // rows row0, row0+1

    // x rows in registers; nontemporal (read exactly once chip-wide)
    f32x4 xv[2][4];
#pragma unroll
    for (int r = 0; r < 2; ++r) {
        const f32x4* x4 = reinterpret_cast<const f32x4*>(x + (size_t)(row0 + r) * FFF_NIN);
#pragma unroll
        for (int c = 0; c < 4; ++c) xv[r][c] = ld_nt4f(&x4[c * 64 + lane]);
    }

    f32x4 acc[2][4];
#pragma unroll
    for (int r = 0; r < 2; ++r)
#pragma unroll
        for (int c = 0; c < 4; ++c) acc[r][c] = (f32x4)(0.f);

    int node[2] = {0, 0};

#pragma unroll
    for (int l = 0; l < FFF_LEVELS; ++l) {
        // ---- w1 fragments for both rows ----
        f32x4 wv[2][4];
#pragma unroll
        for (int r = 0; r < 2; ++r) {
            const f32x4* w14 = reinterpret_cast<const f32x4*>(w1s + (size_t)node[r] * FFF_NIN);
#pragma unroll
            for (int c = 0; c < 4; ++c)
                wv[r][c] = (l >= 9) ? ld_nt4f(&w14[c * 64 + lane]) : w14[c * 64 + lane];
        }

        // ---- dots (same summation order as the passing round-1 kernel) ----
        float p[2];
#pragma unroll
        for (int r = 0; r < 2; ++r) {
            float s = 0.f;
#pragma unroll
            for (int c = 0; c < 4; ++c) {
                s = fmaf(xv[r][c][0], wv[r][c][0], s);
                s = fmaf(xv[r][c][1], wv[r][c][1], s);
                s = fmaf(xv[r][c][2], wv[r][c][2], s);
                s = fmaf(xv[r][c][3], wv[r][c][3], s);
            }
            p[r] = s;
        }

        // ---- issue w2 loads now; latency covered by the reduce chain ----
        u16x4 uvb[2][4];
        f32x4 uvf[2][4];
#pragma unroll
        for (int r = 0; r < 2; ++r) {
            if (W2BF16) {
                const u16x4* w24 = reinterpret_cast<const u16x4*>(
                    (const unsigned short*)w2p + (size_t)node[r] * FFF_NOUT);
#pragma unroll
                for (int c = 0; c < 4; ++c)
                    uvb[r][c] = (l >= 9) ? ld_nt4u(&w24[c * 64 + lane]) : w24[c * 64 + lane];
            } else {
                const f32x4* w24 = reinterpret_cast<const f32x4*>(
                    (const float*)w2p + (size_t)node[r] * FFF_NOUT);
#pragma unroll
                for (int c = 0; c < 4; ++c)
                    uvf[r][c] = (l >= 9) ? ld_nt4f(&w24[c * 64 + lane]) : w24[c * 64 + lane];
            }
        }

        // ---- interleaved 64-lane butterfly reduce (two independent chains) ----
#pragma unroll
        for (int m = 1; m < 64; m <<= 1) {
            const float t0 = __shfl_xor(p[0], m, 64);
            const float t1 = __shfl_xor(p[1], m, 64);
            p[0] += t0;
            p[1] += t1;
        }

        // ---- accumulate y, advance nodes ----
#pragma unroll
        for (int r = 0; r < 2; ++r) {
            const float score = p[r];
#pragma unroll
            for (int c = 0; c < 4; ++c) {
                f32x4 w;
                if (W2BF16) {
                    w[0] = __uint_as_float((unsigned)uvb[r][c][0] << 16);
                    w[1] = __uint_as_float((unsigned)uvb[r][c][1] << 16);
                    w[2] = __uint_as_float((unsigned)uvb[r][c][2] << 16);
                    w[3] = __uint_as_float((unsigned)uvb[r][c][3] << 16);
                } else {
                    w = uvf[r][c];
                }
                acc[r][c][0] = fmaf(score, w[0], acc[r][c][0]);
                acc[r][c][1] = fmaf(score, w[1], acc[r][c][1]);
                acc[r][c][2] = fmaf(score, w[2], acc[r][c][2]);
                acc[r][c][3] = fmaf(score, w[3], acc[r][c][3]);
            }
            node[r] = node[r] * 2 + 1 + ((score > 0.f) ? 1 : 0);
        }
    }

    // ---- store y (nontemporal: written once, never re-read) ----
#pragma unroll
    for (int r = 0; r < 2; ++r) {
        f32x4* y4 = reinterpret_cast<f32x4*>(y + (size_t)(row0 + r) * FFF_NOUT);
#pragma unroll
        for (int c = 0; c < 4; ++c)
            __builtin_nontemporal_store(acc[r][c], &y4[c * 64 + lane]);
    }
}

extern "C" void kernel_launch(void* const* d_in, const int* in_sizes, int n_in,
                              void* d_out, int out_size, void* d_ws, size_t ws_size,
                              hipStream_t stream) {
    const float* x   = (const float*)d_in[0];
    const float* w1s = (const float*)d_in[1];
    const float* w2s = (const float*)d_in[2];
    float* y = (float*)d_out;

    const size_t w2b_bytes = (size_t)FFF_NODES * FFF_NOUT * sizeof(unsigned short);
    const int blocks = FFF_BATCH / 8;   // 4 waves/block x 2 rows/wave

    if (ws_size >= w2b_bytes) {
        unsigned short* w2b = (unsigned short*)d_ws;
        // 2047*1024 floats = 524032 float4 = 2047 blocks x 256 threads exactly
        fff_w2_to_bf16<<<FFF_NODES, 256, 0, stream>>>(w2s, w2b);
        fff_main<true><<<blocks, 256, 0, stream>>>(x, w1s, (const void*)w2b, y);
    } else {
        fff_main<false><<<blocks, 256, 0, stream>>>(x, w1s, (const void*)w2s, y);
    }
}